// Round 15
// baseline (128.310 us; speedup 1.0000x reference)
//
#include <hip/hip_runtime.h>
#include <math.h>

#define O_CH 32
#define I_CH 3
#define IH 512
#define IW 512
#define OH 510
#define OW 510
#define N_IMG 16

typedef float v2f __attribute__((ext_vector_type(2)));
typedef float v4f __attribute__((ext_vector_type(4)));

// 16B store with only 8B-guaranteed alignment (CDNA global_store_dwordx4
// needs only dword alignment; memcpy lets clang emit one dwordx4).
__device__ __forceinline__ void store16(float* p, v4f v) {
  __builtin_memcpy((void*)p, &v, 16);
}

// Single fused kernel (R13 base = best, 125.8us) + explicit weight
// double-buffer (R14 delta): rotate nw[7] (o+1 weights, prefetched
// unconditionally from a 33-row padded sW) into w[7] at iteration top, so
// the lgkmcnt wait lands on ds_reads issued one FULL iteration (~432 cyc of
// pk-FMA) earlier — inter-o LDS latency guaranteed hidden instead of
// resurfacing at each unroll-pair boundary.
// Established laws baked in: all 32 o per register-held window (R6: 2.6x);
// 16 px/lane L/R pk-pair axis (R9 > R4 > R10); sequential phase-aligned o
// (R11: stagger hurts L2 writeback); NO min-waves launch_bounds (R5/R7:
// hipcc over-squeezes, window spills, 7-20x fetch); regular stores (R3:
// nt doubles WRITE_SIZE); fused weights (R12: -5us vs separate kernel).
// XCD chunk swizzle: 1024 blocks, q=128 = exactly 2 images per XCD.
__global__ __launch_bounds__(256) void gabor_conv_kernel(
    const float* __restrict__ in,
    const float* __restrict__ freq, const float* __restrict__ theta,
    const float* __restrict__ psi, const float* __restrict__ sigma,
    float* __restrict__ out) {
  __shared__ float sW[O_CH + 1][28];   // +1 pad row: o=31's prefetch target

  const int tid = threadIdx.x;
  // Compute all O*I*9 = 864 weights in-block (exact reference math, PI=3.14)
  for (int i = tid; i < O_CH * I_CH * 9; i += 256) {
    int o = i / 27;
    int rem = i % 27;            // rem = c*9 + kh*3 + kw
    int kh = (rem / 3) % 3;
    int kw = rem % 3;
    // linspace(-ceil(3/2)+1, ceil(3/2), 3) = {-1, 0.5, 2}
    float x = (kw == 0) ? -1.0f : (kw == 1 ? 0.5f : 2.0f);
    float y = (kh == 0) ? -1.0f : (kh == 1 ? 0.5f : 2.0f);
    int pi = o * I_CH + rem / 9; // (O,I) parameter index
    float th = theta[pi], f = freq[pi], p = psi[pi], s = sigma[pi];
    float ct = cosf(th), st = sinf(th);
    float rotx = x * ct + y * st;
    float roty = -x * st + y * ct;
    float se = s + 0.001f;
    float g = expf(-0.5f * (rotx * rotx + roty * roty) / (se * se));
    g *= cosf(f * rotx + p);
    g /= (2.0f * 3.14f * s * s);   // reference uses PI = 3.14 exactly
    sW[o][rem] = g;
  }
  if (tid < O_CH + 1) sW[tid][27] = 0.0f;   // pad col
  if (tid < 27) sW[O_CH][tid] = 0.0f;       // pad row (prefetched, unused)
  __syncthreads();

  const int wave = tid >> 6;   // 0..3
  const int lane = tid & 63;

  // bijective chunked XCD swizzle: 1024 blocks, 128 per XCD (= 2 images)
  const int bid = blockIdx.x;
  const int nid = (bid & 7) * 128 + (bid >> 3);
  const int n = nid >> 6;                  // image 0..15
  const int y = (nid & 63) * 8 + wave * 2; // even top row of this wave's pair
  if (y + 1 >= OH) return;                 // only tail-block wave 3 (y=510)

  const int x0 = lane * 4;                 // L px x0..x0+3; R px +256
  const float* inN = in + (size_t)n * (I_CH * IH * IW);

  // Window as (L,R) column pairs: 3 ch x 4 rows x 6 cols = 72 v2f
  v2f P[I_CH][4][6];
#pragma unroll
  for (int c = 0; c < I_CH; ++c) {
#pragma unroll
    for (int rw = 0; rw < 4; ++rw) {
      const float* rowp = inN + ((size_t)c * IH + y + rw) * IW;
      v4f LA = *(const v4f*)&rowp[x0];          // cols x0..x0+3 (16B aligned)
      v2f LB = *(const v2f*)&rowp[x0 + 4];      // cols x0+4,x0+5
      v4f RA = *(const v4f*)&rowp[x0 + 256];    // cols x0+256..+259
      int xc = x0 + 260; if (xc > IW - 2) xc = IW - 2;  // lane63: 512 -> 510
      v2f RB = *(const v2f*)&rowp[xc];
      P[c][rw][0] = (v2f){LA.x, RA.x};
      P[c][rw][1] = (v2f){LA.y, RA.y};
      P[c][rw][2] = (v2f){LA.z, RA.z};
      P[c][rw][3] = (v2f){LA.w, RA.w};
      P[c][rw][4] = (v2f){LB.x, RB.x};
      P[c][rw][5] = (v2f){LB.y, RB.y};
    }
  }

  const bool full = (lane != 63);   // lane63 R px 510,511 are OOB
  float* op = out + (((size_t)n * O_CH * OH) + y) * OW + x0;  // o=0, row y, L

  // Weight double-buffer: nw holds o's weights at iteration top.
  v4f nw0, nw1, nw2, nw3, nw4, nw5, nw6;
  {
    const v4f* s4 = (const v4f*)&sW[0][0];
    nw0 = s4[0]; nw1 = s4[1]; nw2 = s4[2]; nw3 = s4[3];
    nw4 = s4[4]; nw5 = s4[5]; nw6 = s4[6];
  }

#define WQ(i) ((i) < 4 ? w0[(i)] : (i) < 8 ? w1[(i) - 4] : (i) < 12 ? w2[(i) - 8] : \
               (i) < 16 ? w3[(i) - 12] : (i) < 20 ? w4[(i) - 16] : \
               (i) < 24 ? w5[(i) - 20] : w6[(i) - 24])

#pragma unroll 2
  for (int o = 0; o < O_CH; ++o) {
    // rotate: w <- nw (this o's weights; lgkm wait covered by prev FMA burst)
    v4f w0 = nw0, w1 = nw1, w2 = nw2, w3 = nw3, w4 = nw4, w5 = nw5, w6 = nw6;
    // prefetch o+1 unconditionally (row 32 = pad, read but never used)
    {
      const v4f* s4 = (const v4f*)&sW[o + 1][0];
      nw0 = s4[0]; nw1 = s4[1]; nw2 = s4[2]; nw3 = s4[3];
      nw4 = s4[4]; nw5 = s4[5]; nw6 = s4[6];
    }
    v2f a0[4], a1[4];
#pragma unroll
    for (int j = 0; j < 4; ++j) { a0[j] = (v2f){0.f, 0.f}; a1[j] = (v2f){0.f, 0.f}; }
#pragma unroll
    for (int c = 0; c < I_CH; ++c) {
#pragma unroll
      for (int kh = 0; kh < 3; ++kh) {
#pragma unroll
        for (int kw = 0; kw < 3; ++kw) {
          float wt = WQ(c * 9 + kh * 3 + kw);
          v2f wv = (v2f){wt, wt};
#pragma unroll
          for (int j = 0; j < 4; ++j) {      // 8 v_pk_fma_f32 per tap
            a0[j] = __builtin_elementwise_fma(P[c][kh + 0][kw + j], wv, a0[j]);
            a1[j] = __builtin_elementwise_fma(P[c][kh + 1][kw + j], wv, a1[j]);
          }
        }
      }
    }
    // unpack (L,R) pairs into row-contiguous quads
    v4f L0 = (v4f){a0[0].x, a0[1].x, a0[2].x, a0[3].x};
    v4f R0 = (v4f){a0[0].y, a0[1].y, a0[2].y, a0[3].y};
    v4f L1 = (v4f){a1[0].x, a1[1].x, a1[2].x, a1[3].x};
    v4f R1 = (v4f){a1[0].y, a1[1].y, a1[2].y, a1[3].y};
    store16(op, L0);
    store16(op + OW, L1);
    if (full) {
      store16(op + 256, R0);
      store16(op + OW + 256, R1);
    } else {
      *(v2f*)(op + 256)      = (v2f){R0.x, R0.y};   // px 508,509
      *(v2f*)(op + OW + 256) = (v2f){R1.x, R1.y};
    }
    op += (size_t)(OH * OW);
  }
#undef WQ
}

extern "C" void kernel_launch(void* const* d_in, const int* in_sizes, int n_in,
                              void* d_out, int out_size, void* d_ws, size_t ws_size,
                              hipStream_t stream) {
  const float* img   = (const float*)d_in[0];
  const float* freq  = (const float*)d_in[1];
  const float* theta = (const float*)d_in[2];
  const float* psi   = (const float*)d_in[3];
  const float* sigma = (const float*)d_in[4];
  float* outp = (float*)d_out;

  dim3 grid(N_IMG * 64);   // 1024 blocks; block = 8 rows (4 waves x row-pair)
  gabor_conv_kernel<<<grid, dim3(256), 0, stream>>>(img, freq, theta, psi,
                                                    sigma, outp);
}